// Round 5
// baseline (268.074 us; speedup 1.0000x reference)
//
#include <hip/hip_runtime.h>

// QuantizedLinear: out[64,11008] = x[64,4096] @ (Wq*scale)^T + bias
// v6: barrier-free wave-private streaming GEMM, single-pass epilogue.
// Rounds 0-4 evidence: 4 structurally different GEMMs all 259-264 us; the
// invariant was {4-wave barrier lockstep, K-split atomic epilogue, bias-init}.
// v6 removes all three:
//   grid = 688 blocks (N/16), 4 waves split K (1024 each). Weights staged
//   HBM->LDS via gload_lds into WAVE-PRIVATE 2x4KB buffers -> no main-loop
//   barriers; counted s_waitcnt vmcnt(12) per tile is wave-exact. x fragments
//   reg-prefetched one tile ahead from L2-resident bf16 copy (d_ws, prep
//   kernel). End: cross-wave LDS reduce (v3-verified) + scale+bias + store.
// Fixed harness cost ~212 us (2 poison fills @ ~106 us, 85% HBM peak, every
// top-5 entry). Our portion ~50 us at v5; target ~37 (weights 180 MB @ ~6 TB/s).

#define M_DIM 64
#define N_DIM 11008
#define K_DIM 4096
#define BLOCK_N 16
#define NBLOCKS (N_DIM / BLOCK_N)   // 688
#define KW (K_DIM / 4)              // 1024 k per wave
#define BK 64                       // k per staged tile
#define NT (KW / BK)                // 16 tiles per wave
#define WTILE_B (16 * 256)          // 16 rows x 64 int32 = 4096 B per buffer

typedef __attribute__((ext_vector_type(8))) short bf16x8;
typedef __attribute__((ext_vector_type(8))) short s16x8;
typedef __attribute__((ext_vector_type(4))) float f32x4;
typedef __attribute__((ext_vector_type(4))) int i32x4;
typedef __attribute__((ext_vector_type(4))) short s16x4;

// int in [-128,127] -> bf16 is EXACT: cvt to f32, truncate mantissa
__device__ __forceinline__ short i2bf(int q) {
    float f = (float)q;
    return (short)(__builtin_bit_cast(unsigned int, f) >> 16);
}

// RNE float -> bf16
__device__ __forceinline__ short f2bf(float f) {
    unsigned int u = __builtin_bit_cast(unsigned int, f);
    u = u + 0x7FFFu + ((u >> 16) & 1u);
    return (short)(u >> 16);
}

// async global->LDS, 16 B per lane. LDS dest: wave-uniform base + lane*16.
__device__ __forceinline__ void load_lds_16B(const void* g, void* l) {
    __builtin_amdgcn_global_load_lds(
        (const __attribute__((address_space(1))) unsigned int*)g,
        (__attribute__((address_space(3))) unsigned int*)l,
        16, 0, 0);
}

// ---- prep: x f32 -> bf16 once (512 KB into d_ws). 8 elems/thread. ----
__global__ __launch_bounds__(256) void xcvt_kernel(const float* __restrict__ x,
                                                   short* __restrict__ xbf) {
    int idx = (blockIdx.x * 256 + threadIdx.x) * 8;
    f32x4 a = *(const f32x4*)(x + idx);
    f32x4 b = *(const f32x4*)(x + idx + 4);
    s16x8 h;
    h[0] = f2bf(a.x); h[1] = f2bf(a.y); h[2] = f2bf(a.z); h[3] = f2bf(a.w);
    h[4] = f2bf(b.x); h[5] = f2bf(b.y); h[6] = f2bf(b.z); h[7] = f2bf(b.w);
    *(s16x8*)(xbf + idx) = h;
}

// ---- stage one 16-row x BK weight tile into wave-private LDS (4 gload_lds) ----
// Global source col pre-swizzled by ((row&7)<<4) so the swizzled READ is
// conflict-free (rule 21: same involution both sides; linear LDS dest).
__device__ __forceinline__ void stage_w(const int* __restrict__ wq, int n0, int kA,
                                        char* wl, int lane) {
    #pragma unroll
    for (int j = 0; j < 4; ++j) {               // 4 rows per instr, 16 lanes x 16B
        int row  = j * 4 + (lane >> 4);
        int colb = ((lane & 15) * 16) ^ ((row & 7) << 4);
        const char* g = (const char*)(wq + (size_t)(n0 + row) * K_DIM + kA) + colb;
        load_lds_16B(g, wl + j * 1024);
    }
}

// ---- prefetch next tile's 8 x-fragments into registers (8 VMEM) ----
__device__ __forceinline__ void xpref(const short* __restrict__ xbf, int kA,
                                      int l16, int quad, bf16x8 (&xb)[8]) {
    #pragma unroll
    for (int i = 0; i < 8; ++i) {               // i = h*4 + mi
        int mi = i & 3;
        int kk = (i >> 2) * 32;
        xb[i] = *(const bf16x8*)(xbf + (size_t)(mi * 16 + l16) * K_DIM + kA + kk + quad * 8);
    }
}

// ---- compute one BK=64 tile: 2 k-steps x 4 mi MFMA ----
__device__ __forceinline__ void compute_t(const char* wl, const bf16x8 (&xb)[8],
                                          f32x4 (&acc)[4], int l16, int quad) {
    const int wsw = (l16 & 7) << 4;
    #pragma unroll
    for (int h = 0; h < 2; ++h) {
        const int L0 = (h * 32 + quad * 8) * 4;   // logical byte in 256B row
        i32x4 b0 = *(const i32x4*)(wl + l16 * 256 + ((L0)      ^ wsw));
        i32x4 b1 = *(const i32x4*)(wl + l16 * 256 + ((L0 + 16) ^ wsw));
        bf16x8 bfrag;
        bfrag[0] = i2bf(b0.x); bfrag[1] = i2bf(b0.y);
        bfrag[2] = i2bf(b0.z); bfrag[3] = i2bf(b0.w);
        bfrag[4] = i2bf(b1.x); bfrag[5] = i2bf(b1.y);
        bfrag[6] = i2bf(b1.z); bfrag[7] = i2bf(b1.w);
        #pragma unroll
        for (int mi = 0; mi < 4; ++mi) {
            acc[mi] = __builtin_amdgcn_mfma_f32_16x16x32_bf16(xb[h * 4 + mi], bfrag, acc[mi], 0, 0, 0);
        }
    }
}

// ---- v6 GEMM ----
__global__ __launch_bounds__(256) void qlinear_v6_kernel(const short* __restrict__ xbf,
                                                         const int* __restrict__ wq,
                                                         const float* __restrict__ scale_p,
                                                         const float* __restrict__ bias,
                                                         float* __restrict__ out) {
    // 4 waves x 2 x 4KB private weight buffers = 32 KB. The first 16 KB is
    // reused for the cross-wave reduce AFTER a full __syncthreads.
    __shared__ char smem[4 * 2 * WTILE_B];

    const int tid  = threadIdx.x;
    const int wave = tid >> 6;
    const int lane = tid & 63;
    const int quad = lane >> 4;
    const int l16  = lane & 15;

    const int n0 = blockIdx.x * BLOCK_N;
    const int k0 = wave * KW;

    char* buf0 = smem + wave * 2 * WTILE_B;
    char* buf1 = buf0 + WTILE_B;

    f32x4 acc[4] = {f32x4{0,0,0,0}, f32x4{0,0,0,0}, f32x4{0,0,0,0}, f32x4{0,0,0,0}};
    bf16x8 xa[8], xb[8];   // static double-buffer (rule 20: named, never runtime-indexed)

    // prologue: tile 0 -> xa/buf0
    xpref(xbf, k0, l16, quad, xa);
    stage_w(wq, n0, k0, buf0, lane);

    // main loop: 2 tiles per iteration, wave-private, no barriers.
    // Per tile in flight: 8 x-loads + 4 gload_lds = 12 VMEM; vmcnt(12) waits
    // exactly for the PREVIOUS tile's 12 while the new 12 stream.
    for (int t = 0; t < NT - 2; t += 2) {
        xpref(xbf, k0 + (t + 1) * BK, l16, quad, xb);
        stage_w(wq, n0, k0 + (t + 1) * BK, buf1, lane);
        asm volatile("s_waitcnt vmcnt(12)" ::: "memory");
        __builtin_amdgcn_sched_barrier(0);
        compute_t(buf0, xa, acc, l16, quad);

        xpref(xbf, k0 + (t + 2) * BK, l16, quad, xa);
        stage_w(wq, n0, k0 + (t + 2) * BK, buf0, lane);
        asm volatile("s_waitcnt vmcnt(12)" ::: "memory");
        __builtin_amdgcn_sched_barrier(0);
        compute_t(buf1, xb, acc, l16, quad);
    }
    // tail: tiles NT-2 (buf0/xa) and NT-1 (buf1/xb)
    xpref(xbf, k0 + (NT - 1) * BK, l16, quad, xb);
    stage_w(wq, n0, k0 + (NT - 1) * BK, buf1, lane);
    asm volatile("s_waitcnt vmcnt(12)" ::: "memory");
    __builtin_amdgcn_sched_barrier(0);
    compute_t(buf0, xa, acc, l16, quad);
    asm volatile("s_waitcnt vmcnt(0)" ::: "memory");
    __builtin_amdgcn_sched_barrier(0);
    compute_t(buf1, xb, acc, l16, quad);

    // ---- cross-wave reduce (v3-verified mapping), fused scale+bias+store ----
    __syncthreads();                       // all waves done with weight buffers
    float* red = (float*)smem;             // [4][64][16] f32 = 16 KB
    #pragma unroll
    for (int mi = 0; mi < 4; ++mi) {
        #pragma unroll
        for (int r = 0; r < 4; ++r) {
            int m = mi * 16 + quad * 4 + r;
            red[(wave * M_DIM + m) * BLOCK_N + l16] = acc[mi][r];
        }
    }
    __syncthreads();
    {
        const float scale = *scale_p;
        int idx = tid * 4;                 // over the 64x16 tile
        int m = idx >> 4;
        int n = idx & 15;                  // 0,4,8,12
        f32x4 s0 = *(const f32x4*)&red[(0 * M_DIM + m) * BLOCK_N + n];
        f32x4 s1 = *(const f32x4*)&red[(1 * M_DIM + m) * BLOCK_N + n];
        f32x4 s2 = *(const f32x4*)&red[(2 * M_DIM + m) * BLOCK_N + n];
        f32x4 s3 = *(const f32x4*)&red[(3 * M_DIM + m) * BLOCK_N + n];
        f32x4 bb = *(const f32x4*)(bias + n0 + n);
        f32x4 r;
        r.x = (s0.x + s1.x + s2.x + s3.x) * scale + bb.x;
        r.y = (s0.y + s1.y + s2.y + s3.y) * scale + bb.y;
        r.z = (s0.z + s1.z + s2.z + s3.z) * scale + bb.z;
        r.w = (s0.w + s1.w + s2.w + s3.w) * scale + bb.w;
        *(f32x4*)(out + (size_t)m * N_DIM + n0 + n) = r;
    }
}

// ---------------------------------------------------------------------------
// Fallback (round-0 verified) if d_ws can't hold the 512 KB bf16 x.
// ---------------------------------------------------------------------------
#define KSPLIT 8
#define KC (K_DIM / KSPLIT)
#define FB_BK 128
#define LDS_STRIDE 136
#define FB_BLOCK_N 64

__global__ __launch_bounds__(256) void init_bias_kernel(const float* __restrict__ bias,
                                                        float* __restrict__ out) {
    int idx = blockIdx.x * 256 + threadIdx.x;
    int col4 = idx % 2752;
    f32x4 b = *(const f32x4*)(bias + col4 * 4);
    *(f32x4*)(out + (size_t)idx * 4) = b;
}

__global__ __launch_bounds__(256) void qlinear_atomic_kernel(const float* __restrict__ x,
                                                             const int* __restrict__ wq,
                                                             const float* __restrict__ scale_p,
                                                             float* __restrict__ out) {
    __shared__ short lds[M_DIM * LDS_STRIDE];

    const int tid  = threadIdx.x;
    const int wave = tid >> 6;
    const int lane = tid & 63;
    const int quad = lane >> 4;
    const int l16  = lane & 15;

    const int n0  = blockIdx.x * FB_BLOCK_N;
    const int kc0 = blockIdx.y * KC;
    const float scale = *scale_p;

    const int nw = n0 + wave * 16 + l16;
    const int* wptr = wq + (size_t)nw * K_DIM + kc0 + quad * 8;

    f32x4 acc[4] = {f32x4{0,0,0,0}, f32x4{0,0,0,0}, f32x4{0,0,0,0}, f32x4{0,0,0,0}};

    for (int kb = 0; kb < KC; kb += FB_BK) {
        {
            const float* xbase = x + kc0 + kb;
            #pragma unroll
            for (int j = 0; j < 8; ++j) {
                int f  = tid + j * 256;
                int row = f >> 5;
                int c4  = f & 31;
                f32x4 v = *(const f32x4*)(xbase + (size_t)row * K_DIM + c4 * 4);
                s16x4 h;
                h.x = f2bf(v.x); h.y = f2bf(v.y); h.z = f2bf(v.z); h.w = f2bf(v.w);
                *(s16x4*)&lds[row * LDS_STRIDE + c4 * 4] = h;
            }
        }
        __syncthreads();

        #pragma unroll
        for (int kk = 0; kk < FB_BK; kk += 32) {
            i32x4 b0 = *(const i32x4*)(wptr + kb + kk);
            i32x4 b1 = *(const i32x4*)(wptr + kb + kk + 4);
            bf16x8 bfrag;
            bfrag[0] = i2bf(b0.x); bfrag[1] = i2bf(b0.y);
            bfrag[2] = i2bf(b0.z); bfrag[3] = i2bf(b0.w);
            bfrag[4] = i2bf(b1.x); bfrag[5] = i2bf(b1.y);
            bfrag[6] = i2bf(b1.z); bfrag[7] = i2bf(b1.w);

            #pragma unroll
            for (int mi = 0; mi < 4; ++mi) {
                bf16x8 afrag = *(const bf16x8*)&lds[(mi * 16 + l16) * LDS_STRIDE + kk + quad * 8];
                acc[mi] = __builtin_amdgcn_mfma_f32_16x16x32_bf16(afrag, bfrag, acc[mi], 0, 0, 0);
            }
        }
        __syncthreads();
    }

    const int nout = n0 + wave * 16 + l16;
    #pragma unroll
    for (int mi = 0; mi < 4; ++mi) {
        #pragma unroll
        for (int r = 0; r < 4; ++r) {
            int m = mi * 16 + quad * 4 + r;
            atomicAdd(&out[(size_t)m * N_DIM + nout], acc[mi][r] * scale);
        }
    }
}

extern "C" void kernel_launch(void* const* d_in, const int* in_sizes, int n_in,
                              void* d_out, int out_size, void* d_ws, size_t ws_size,
                              hipStream_t stream) {
    const float* x      = (const float*)d_in[0];
    const int*   wq     = (const int*)d_in[1];
    const float* scale  = (const float*)d_in[2];
    const float* bias   = (const float*)d_in[3];
    float* out = (float*)d_out;

    const size_t xbf_bytes = (size_t)M_DIM * K_DIM * sizeof(short);  // 512 KB

    if (ws_size >= xbf_bytes && d_ws != nullptr) {
        short* xbf = (short*)d_ws;
        // 1) x -> bf16 once (128 blocks)
        xcvt_kernel<<<(M_DIM * K_DIM) / (256 * 8), 256, 0, stream>>>(x, xbf);
        // 2) barrier-free streaming GEMM, direct store (no init, no atomics)
        qlinear_v6_kernel<<<NBLOCKS, 256, 0, stream>>>(xbf, wq, scale, bias, out);
    } else {
        init_bias_kernel<<<688, 256, 0, stream>>>(bias, out);
        dim3 grid(N_DIM / FB_BLOCK_N, KSPLIT);
        qlinear_atomic_kernel<<<grid, 256, 0, stream>>>(x, wq, scale, out);
    }
}